// Round 10
// baseline (3523.473 us; speedup 1.0000x reference)
//
#include <hip/hip_runtime.h>
#include <stdint.h>

// Problem constants (from reference setup_inputs)
#define M_TOK 8192
#define N_OUT 4096
#define K_IN  4096

// GEMM tiling: 256x256 tile, BK=64, double-buffered LDS (128 KiB), 8 waves 2x4
#define BM 256
#define BN 256
#define BK 64
#define NT (K_IN / BK)            // 64 K-tiles
#define BUF 32768                 // shorts per buffer (64 KiB)
#define SEC 8192                  // shorts per k-slice section (256 rows x 32)

typedef float floatx4 __attribute__((ext_vector_type(4)));
typedef __bf16 bf16x8 __attribute__((ext_vector_type(8)));
typedef unsigned short ushort8_t __attribute__((ext_vector_type(8)));

#define MFMA16 __builtin_amdgcn_mfma_f32_16x16x32_bf16

// ---------- helpers ----------

__device__ __forceinline__ unsigned short f32_to_bf16_rne(float f) {
    union { float f; unsigned int u; } v; v.f = f;
    unsigned int u = v.u;
    u += 0x7FFFu + ((u >> 16) & 1u);   // round-to-nearest-even; inputs have no NaN
    return (unsigned short)(u >> 16);
}

// async global->LDS, 16 bytes per lane. LDS side is wave-uniform base + lane*16.
__device__ __forceinline__ void async_copy16(const void* g, void* l) {
    __builtin_amdgcn_global_load_lds(
        (__attribute__((address_space(1))) void*)(g),
        (__attribute__((address_space(3))) void*)(l),
        16, 0, 0);
}

// ---------- pre-pass: fp32 -> bf16 ----------

__global__ void cvt_f32_bf16_kernel(const float* __restrict__ in,
                                    unsigned short* __restrict__ out, int n8) {
    int i = blockIdx.x * 256 + threadIdx.x;
    if (i >= n8) return;
    const float4* p = (const float4*)in + (size_t)i * 2;
    float4 a = p[0];
    float4 b = p[1];
    ushort8_t o;
    o[0] = f32_to_bf16_rne(a.x); o[1] = f32_to_bf16_rne(a.y);
    o[2] = f32_to_bf16_rne(a.z); o[3] = f32_to_bf16_rne(a.w);
    o[4] = f32_to_bf16_rne(b.x); o[5] = f32_to_bf16_rne(b.y);
    o[6] = f32_to_bf16_rne(b.z); o[7] = f32_to_bf16_rne(b.w);
    *((ushort8_t*)out + i) = o;
}

// ---------- pre-pass: int32 (int8-valued) -> bf16 (exact) ----------

__global__ void cvt_i32_bf16_kernel(const int* __restrict__ in,
                                    unsigned short* __restrict__ out, int n8) {
    int i = blockIdx.x * 256 + threadIdx.x;
    if (i >= n8) return;
    const int4* p = (const int4*)in + (size_t)i * 2;
    int4 a = p[0];
    int4 b = p[1];
    ushort8_t o;
    o[0] = f32_to_bf16_rne((float)a.x); o[1] = f32_to_bf16_rne((float)a.y);
    o[2] = f32_to_bf16_rne((float)a.z); o[3] = f32_to_bf16_rne((float)a.w);
    o[4] = f32_to_bf16_rne((float)b.x); o[5] = f32_to_bf16_rne((float)b.y);
    o[6] = f32_to_bf16_rne((float)b.z); o[7] = f32_to_bf16_rne((float)b.w);
    *((ushort8_t*)out + i) = o;
}

// ---------- GEMM: C[m][n] = sum_k A[m][k]*B[n][k]; C = acc*scale[n]+bias[n] ----------
// ROLE-SPLIT SCHEDULE (fixes the R4-R8 DS<->MFMA alternation): per half-tile
// region, waves 0-3 (group A) run {read next slice (12 ds_read_b128),
// lgkmcnt(12), 32 MFMA} while waves 4-7 (group B) run {lgkmcnt(0), 32 MFMA,
// read next slice}. Each SIMD hosts one A-wave and one B-wave (round-robin
// wave->SIMD), so one wave's MFMA burst always overlaps the other's DS reads
// -- CU-level pipe overlap by construction, not scheduler luck.
// Barriers are OUTSIDE the (wave-uniform) group branch -- no divergent-barrier
// hazard. Accumulation order s0 then s1 per tile: bit-identical to R4/R6/R7.
//
// Per tile: 2 barriers (mid publishes buf(t+1); boundary retires buf(t)),
// 1 vmcnt(0) at mid (drains the 8 stage loads issued ~1000 cyc earlier at
// region-s0 start). Hazards: (a) stage(t+2)->buf(t) issues after the boundary
// barrier; all buf(t) reads (A: region-s1 lgkm(12); B: region-s1 lgkm(0))
// drained before it. (b) reads of buf(t+1) (A: region-s1 after mid barrier;
// B: end of region-s1) come after every wave's vmcnt(0)+mid-barrier. (c) B's
// cross-barrier outstanding reads target buf(t+1), disjoint from stage(t+2).
//
// LDS: k-slice sections A_s0 | A_s1 | B_s0 | B_s1, 16 KiB each, PAIR-ROW
// swizzle (R3/R4-verified 0 conflicts): pair p = row>>1 (128 B) holds rows
// {2p,2p+1}; chunk (p,c): cg = c ^ (p&7); inverse on the per-lane GLOBAL
// source, linear LDS dest. Every ds_read_b128 covers one contiguous 1 KiB
// window exactly once (the R5 lesson).

__global__ __launch_bounds__(512, 2)
void gemm_bf16_kernel(const unsigned short* __restrict__ A,
                      const unsigned short* __restrict__ B,
                      const float* __restrict__ scales,
                      const float* __restrict__ bias,
                      float* __restrict__ C) {
    __shared__ __align__(16) unsigned short lds[2 * BUF];   // 128 KiB

    const int tid = threadIdx.x;

    // T1: bijective XCD swizzle (nwg = 512, divisible by 8), bn-fastest.
    const int nwg = (M_TOK / BM) * (N_OUT / BN);   // 32*16 = 512
    const int cpx = nwg / 8;                        // 64
    const int wg  = (blockIdx.x % 8) * cpx + blockIdx.x / 8;
    const int bn  = wg & 15;                        // N_OUT/BN = 16
    const int bm  = wg >> 4;                        // 0..31

    const int lane = tid & 63;
    const int wave = tid >> 6;          // 0..7
    const int wm   = wave >> 2;         // 0..1 -> rows wm*128 (also: role group)
    const int wn   = wave & 3;          // 0..3 -> cols wn*64

    // ---- staging addressing (loop-invariant; R3-verified) ----
    const int t8 = tid >> 3;                        // 0..63
    const int cg = (tid & 7) ^ (t8 & 7);            // unswizzled chunk in pair
    const int grow0 = 2 * t8 + (cg >> 2);           // row within 128-row issue
    const int gcol0 = (cg & 3) * 8;                 // shorts within k-slice
    const unsigned short* aP = A + (size_t)(bm * BM + grow0) * K_IN + gcol0;
    const unsigned short* bP = B + (size_t)(bn * BN + grow0) * K_IN + gcol0;

    auto stageAll = [&](int tt) {   // 8 global_load_lds: A s0,s1 then B s0,s1
        unsigned short* base = &lds[(tt & 1) * BUF];
#pragma unroll
        for (int s = 0; s < 2; ++s) {
            const unsigned short* ga = aP + tt * BK + s * 32;
            unsigned short* da = base + s * SEC + tid * 8;
            async_copy16(ga, da);
            async_copy16(ga + (size_t)128 * K_IN, da + 4096);
        }
#pragma unroll
        for (int s = 0; s < 2; ++s) {
            const unsigned short* gb = bP + tt * BK + s * 32;
            unsigned short* db = base + 2 * SEC + s * SEC + tid * 8;
            async_copy16(gb, db);
            async_copy16(gb + (size_t)128 * K_IN, db + 4096);
        }
    };

    // ---- fragment read addressing (loop-invariant) ----
    // Frag row R: pair p = R>>1, c = ((R&1)*4 + q) ^ ((R>>1)&7).
    const int r16 = lane & 15;
    const int q   = lane >> 4;                      // 0..3
    const int cr  = (((r16 & 1) << 2) + q) ^ ((r16 >> 1) & 7);
    const int aOff = (wm * 64 + (r16 >> 1)) * 64 + cr * 8;
    const int bOff = 2 * SEC + (wn * 32 + (r16 >> 1)) * 64 + cr * 8;

    floatx4 acc[8][4] = {};
    bf16x8 afX[8], bfX[4], afY[8], bfY[4];   // X = s0 frags, Y = s1 frags

    // read full slice s of buffer base into (af, bf): 12 ds_read_b128
#define RD(af, bf, base, s)                                                    \
    {                                                                          \
        const unsigned short* ar_ = (base) + (s) * SEC + aOff;                 \
        const unsigned short* br_ = (base) + (s) * SEC + bOff;                 \
        _Pragma("unroll")                                                      \
        for (int i = 0; i < 8; ++i) af[i] = *(const bf16x8*)(ar_ + i * 512);   \
        _Pragma("unroll")                                                      \
        for (int j = 0; j < 4; ++j) bf[j] = *(const bf16x8*)(br_ + j * 512);   \
    }
#define MM(af, bf)                                                             \
    {                                                                          \
        __builtin_amdgcn_s_setprio(1);                                         \
        _Pragma("unroll")                                                      \
        for (int i = 0; i < 8; ++i)                                            \
            _Pragma("unroll")                                                  \
            for (int j = 0; j < 4; ++j)                                        \
                acc[i][j] = MFMA16(af[i], bf[j], acc[i][j], 0, 0, 0);          \
        __builtin_amdgcn_s_setprio(0);                                         \
    }

    const bool grpA = (wm == 0);   // wave-uniform role

    // ---- prologue: stage tile 0, publish, everyone reads s0(0) -> X ----
    stageAll(0);
    asm volatile("s_waitcnt vmcnt(0)" ::: "memory");
    __builtin_amdgcn_s_barrier();
    asm volatile("" ::: "memory");
    RD(afX, bfX, lds, 0);

#pragma unroll 1
    for (int t = 0; t < NT; ++t) {
        const unsigned short* Lb  = lds + (t & 1) * BUF;
        const unsigned short* Lb2 = lds + ((t + 1) & 1) * BUF;
        const bool pf = (t + 1 < NT);

        // ================= region (t, s0): consume X, fetch Y ===============
        if (pf) stageAll(t + 1);
        if (grpA) {
            RD(afY, bfY, Lb, 1);                                   // s1(t) -> Y
            asm volatile("s_waitcnt lgkmcnt(12)" ::: "memory");    // drain X
            __builtin_amdgcn_sched_barrier(0);
            MM(afX, bfX);
        } else {
            asm volatile("s_waitcnt lgkmcnt(0)" ::: "memory");     // drain X (old)
            __builtin_amdgcn_sched_barrier(0);
            MM(afX, bfX);
            __builtin_amdgcn_sched_barrier(0);
            RD(afY, bfY, Lb, 1);                                   // s1(t) -> Y
        }
        // mid-tile: publish buf(t+1)
        asm volatile("s_waitcnt vmcnt(0)" ::: "memory");
        __builtin_amdgcn_s_barrier();
        asm volatile("" ::: "memory");

        // ================= region (t, s1): consume Y, fetch next X ==========
        if (grpA) {
            if (pf) {
                RD(afX, bfX, Lb2, 0);                              // s0(t+1) -> X
                asm volatile("s_waitcnt lgkmcnt(12)" ::: "memory");// drain Y
            } else {
                asm volatile("s_waitcnt lgkmcnt(0)" ::: "memory");
            }
            __builtin_amdgcn_sched_barrier(0);
            MM(afY, bfY);
        } else {
            asm volatile("s_waitcnt lgkmcnt(0)" ::: "memory");     // drain Y (old)
            __builtin_amdgcn_sched_barrier(0);
            MM(afY, bfY);
            __builtin_amdgcn_sched_barrier(0);
            if (pf) RD(afX, bfX, Lb2, 0);                          // s0(t+1) -> X
        }
        // boundary: retire buf(t) (all its reads lgkm-drained above)
        __builtin_amdgcn_s_barrier();
        asm volatile("" ::: "memory");
    }

    // ---- epilogue: C/D layout col = lane&15, row = (lane>>4)*4 + reg ----
    const int row0 = bm * BM + wm * 128 + q * 4;
    const int col0 = bn * BN + wn * 64 + r16;
#pragma unroll
    for (int fc = 0; fc < 4; ++fc) {
        const int n  = col0 + fc * 16;
        const float sc = scales[n];
        const float bi = bias[n];
#pragma unroll
        for (int fr = 0; fr < 8; ++fr) {
            const int m = row0 + fr * 16;
#pragma unroll
            for (int r = 0; r < 4; ++r)
                C[(size_t)(m + r) * N_OUT + n] = acc[fr][fc][r] * sc + bi;
        }
    }
}

// ---------- launch ----------

extern "C" void kernel_launch(void* const* d_in, const int* in_sizes, int n_in,
                              void* d_out, int out_size, void* d_ws, size_t ws_size,
                              hipStream_t stream) {
    const float* x      = (const float*)d_in[0];
    const int*   wq     = (const int*)d_in[1];
    const float* scales = (const float*)d_in[2];
    const float* bias   = (const float*)d_in[3];
    float*       out    = (float*)d_out;

    unsigned short* xb = (unsigned short*)d_ws;                       // 64 MiB
    unsigned short* wb = xb + (size_t)M_TOK * K_IN;                   // 32 MiB
    // ws needed: (8192*4096 + 4096*4096) * 2 = 96 MiB

    const int nx8 = (M_TOK * K_IN) / 8;   // 4194304
    const int nw8 = (N_OUT * K_IN) / 8;   // 2097152
    cvt_f32_bf16_kernel<<<nx8 / 256, 256, 0, stream>>>(x, xb, nx8);
    cvt_i32_bf16_kernel<<<nw8 / 256, 256, 0, stream>>>(wq, wb, nw8);

    const int grid = (M_TOK / BM) * (N_OUT / BN);   // 32 * 16 = 512
    gemm_bf16_kernel<<<grid, 512, 0, stream>>>(xb, wb, scales, bias, out);
}

// Round 11
// 1862.968 us; speedup vs baseline: 1.8913x; 1.8913x over previous
//
#include <hip/hip_runtime.h>
#include <stdint.h>

// Problem constants (from reference setup_inputs)
#define M_TOK 8192
#define N_OUT 4096
#define K_IN  4096

// GEMM tiling: 256x256 tile, BK=64, double-buffered LDS (128 KiB), 8 waves 2x4
#define BM 256
#define BN 256
#define BK 64
#define NT (K_IN / BK)            // 64 K-tiles
#define BUF 32768                 // shorts per buffer (64 KiB)
#define SEC 8192                  // shorts per k-slice section (256 rows x 32)

typedef float floatx4 __attribute__((ext_vector_type(4)));
typedef __bf16 bf16x8 __attribute__((ext_vector_type(8)));
typedef unsigned short ushort8_t __attribute__((ext_vector_type(8)));

#define MFMA16 __builtin_amdgcn_mfma_f32_16x16x32_bf16

// ---------- helpers ----------

__device__ __forceinline__ unsigned short f32_to_bf16_rne(float f) {
    union { float f; unsigned int u; } v; v.f = f;
    unsigned int u = v.u;
    u += 0x7FFFu + ((u >> 16) & 1u);   // round-to-nearest-even; inputs have no NaN
    return (unsigned short)(u >> 16);
}

// async global->LDS, 16 bytes per lane. LDS side is wave-uniform base + lane*16.
__device__ __forceinline__ void async_copy16(const void* g, void* l) {
    __builtin_amdgcn_global_load_lds(
        (__attribute__((address_space(1))) void*)(g),
        (__attribute__((address_space(3))) void*)(l),
        16, 0, 0);
}

// ---------- pre-pass: fp32 -> bf16 ----------

__global__ void cvt_f32_bf16_kernel(const float* __restrict__ in,
                                    unsigned short* __restrict__ out, int n8) {
    int i = blockIdx.x * 256 + threadIdx.x;
    if (i >= n8) return;
    const float4* p = (const float4*)in + (size_t)i * 2;
    float4 a = p[0];
    float4 b = p[1];
    ushort8_t o;
    o[0] = f32_to_bf16_rne(a.x); o[1] = f32_to_bf16_rne(a.y);
    o[2] = f32_to_bf16_rne(a.z); o[3] = f32_to_bf16_rne(a.w);
    o[4] = f32_to_bf16_rne(b.x); o[5] = f32_to_bf16_rne(b.y);
    o[6] = f32_to_bf16_rne(b.z); o[7] = f32_to_bf16_rne(b.w);
    *((ushort8_t*)out + i) = o;
}

// ---------- pre-pass: int32 (int8-valued) -> bf16 (exact) ----------

__global__ void cvt_i32_bf16_kernel(const int* __restrict__ in,
                                    unsigned short* __restrict__ out, int n8) {
    int i = blockIdx.x * 256 + threadIdx.x;
    if (i >= n8) return;
    const int4* p = (const int4*)in + (size_t)i * 2;
    int4 a = p[0];
    int4 b = p[1];
    ushort8_t o;
    o[0] = f32_to_bf16_rne((float)a.x); o[1] = f32_to_bf16_rne((float)a.y);
    o[2] = f32_to_bf16_rne((float)a.z); o[3] = f32_to_bf16_rne((float)a.w);
    o[4] = f32_to_bf16_rne((float)b.x); o[5] = f32_to_bf16_rne((float)b.y);
    o[6] = f32_to_bf16_rne((float)b.z); o[7] = f32_to_bf16_rne((float)b.w);
    *((ushort8_t*)out + i) = o;
}

// ---------- GEMM: C[m][n] = sum_k A[m][k]*B[n][k]; C = acc*scale[n]+bias[n] ----------
// ROLE-SPLIT v2 on the R6 skeleton, REGISTER-IDENTICAL to R6 (4-wide frag
// ping-pong, 104 VGPR + 128 acc; R10's 8-wide sets spilled -> 16 GB scratch).
//
// Waves 0-3 (group A, one per SIMD): each phase {issue next reads -> counted
// lgkm -> MFMA} (exact R6 ledger: 4/8/4, boundary lgkm(0)).
// Waves 4-7 (group B, one per SIMD): each phase {lgkmcnt(0) -> MFMA -> issue
// next reads} (reads trail by one phase). On every SIMD one wave is in MFMA
// while the other is in DS-read -> matrix and DS pipes overlap by
// construction instead of the measured lockstep alternation (tile time 4600
// cyc = MFMA 2483 + DS ~2100, zero overlap, R4/R6/R7 all ~identical).
// sched_barrier(0) pins B's read-after-MFMA order (else the compiler hoists
// the loads and restores lockstep).
//
// Sync structure (identical to R6, barriers OUTSIDE the uniform role branch):
// all 8 stage loads for t+1 issued in P1/P2; one {vmcnt(0)+lgkmcnt(0)+
// barrier} at the tile boundary (start of P4). Hazards: every wave's reads of
// buf(t) are lgkm-drained before it reaches the boundary barrier (A: P1-P3
// counted waits + boundary lgkm0; B: each phase's lgkm0 + boundary lgkm0);
// stage(t+2)->buf(t) is issued after that barrier. Reads of buf(t+1) (P4,
// both groups) follow every wave's vmcnt(0)+barrier. Accumulation order
// unchanged -> bit-identical numerics.
//
// LDS: k-slice sections A_s0 | A_s1 | B_s0 | B_s1, 16 KiB each, PAIR-ROW
// swizzle (R3/R4-verified 0 conflicts): pair p = row>>1 (128 B) holds rows
// {2p,2p+1}; chunk (p,c): cg = c ^ (p&7); inverse on the per-lane GLOBAL
// source, linear LDS dest. Every ds_read_b128 covers one contiguous 1 KiB
// window exactly once (the R5 lesson).

__global__ __launch_bounds__(512, 2)
void gemm_bf16_kernel(const unsigned short* __restrict__ A,
                      const unsigned short* __restrict__ B,
                      const float* __restrict__ scales,
                      const float* __restrict__ bias,
                      float* __restrict__ C) {
    __shared__ __align__(16) unsigned short lds[2 * BUF];   // 128 KiB

    const int tid = threadIdx.x;

    // T1: bijective XCD swizzle (nwg = 512, divisible by 8), bn-fastest.
    const int nwg = (M_TOK / BM) * (N_OUT / BN);   // 32*16 = 512
    const int cpx = nwg / 8;                        // 64
    const int wg  = (blockIdx.x % 8) * cpx + blockIdx.x / 8;
    const int bn  = wg & 15;                        // N_OUT/BN = 16
    const int bm  = wg >> 4;                        // 0..31

    const int lane = tid & 63;
    const int wave = tid >> 6;          // 0..7
    const int wm   = wave >> 2;         // 0..1 -> rows wm*128 (also: role group)
    const int wn   = wave & 3;          // 0..3 -> cols wn*64

    // ---- staging addressing (loop-invariant; R3-verified) ----
    const int t8 = tid >> 3;                        // 0..63
    const int cg = (tid & 7) ^ (t8 & 7);            // unswizzled chunk in pair
    const int grow0 = 2 * t8 + (cg >> 2);           // row within 128-row issue
    const int gcol0 = (cg & 3) * 8;                 // shorts within k-slice
    const unsigned short* aP = A + (size_t)(bm * BM + grow0) * K_IN + gcol0;
    const unsigned short* bP = B + (size_t)(bn * BN + grow0) * K_IN + gcol0;

    auto stA = [&](int tt, int s) {
        unsigned short* d = &lds[(tt & 1) * BUF + s * SEC + tid * 8];
        const unsigned short* g = aP + tt * BK + s * 32;
        async_copy16(g, d);
        async_copy16(g + (size_t)128 * K_IN, d + 4096);
    };
    auto stB = [&](int tt, int s) {
        unsigned short* d = &lds[(tt & 1) * BUF + 2 * SEC + s * SEC + tid * 8];
        const unsigned short* g = bP + tt * BK + s * 32;
        async_copy16(g, d);
        async_copy16(g + (size_t)128 * K_IN, d + 4096);
    };

    // ---- fragment read addressing (loop-invariant) ----
    // Frag row R: pair p = R>>1, c = ((R&1)*4 + q) ^ ((R>>1)&7).
    const int r16 = lane & 15;
    const int q   = lane >> 4;                      // 0..3
    const int cr  = (((r16 & 1) << 2) + q) ^ ((r16 >> 1) & 7);
    const int aOff = (wm * 64 + (r16 >> 1)) * 64 + cr * 8;
    const int bOff = 2 * SEC + (wn * 32 + (r16 >> 1)) * 64 + cr * 8;

    floatx4 acc[8][4] = {};
    bf16x8 afA[4], afB[4], bfA[4], bfB[4];

    // ---- read/MFMA building blocks (4-wide sets, R6 shapes) ----
#define RD_A03(dst, base, s)                                                   \
    { _Pragma("unroll") for (int i = 0; i < 4; ++i)                            \
        dst[i] = *(const bf16x8*)((base) + (s) * SEC + aOff + i * 512); }
#define RD_A47(dst, base, s)                                                   \
    { _Pragma("unroll") for (int i = 0; i < 4; ++i)                            \
        dst[i] = *(const bf16x8*)((base) + (s) * SEC + aOff + (4 + i) * 512); }
#define RD_BF(dst, base, s)                                                    \
    { _Pragma("unroll") for (int j = 0; j < 4; ++j)                            \
        dst[j] = *(const bf16x8*)((base) + (s) * SEC + bOff + j * 512); }
#define MM03(af, bf)                                                           \
    { __builtin_amdgcn_s_setprio(1);                                           \
      _Pragma("unroll") for (int i = 0; i < 4; ++i)                            \
          _Pragma("unroll") for (int j = 0; j < 4; ++j)                        \
              acc[i][j] = MFMA16(af[i], bf[j], acc[i][j], 0, 0, 0);            \
      __builtin_amdgcn_s_setprio(0); }
#define MM47(af, bf)                                                           \
    { __builtin_amdgcn_s_setprio(1);                                           \
      _Pragma("unroll") for (int i = 0; i < 4; ++i)                            \
          _Pragma("unroll") for (int j = 0; j < 4; ++j)                        \
              acc[4 + i][j] = MFMA16(af[i], bf[j], acc[4 + i][j], 0, 0, 0);    \
      __builtin_amdgcn_s_setprio(0); }
#define SBAR __builtin_amdgcn_sched_barrier(0)
#define LGKM(n) asm volatile("s_waitcnt lgkmcnt(" #n ")" ::: "memory")

    const bool grpA = (wm == 0);   // wave-uniform role

    // ---- prologue: stage tile 0, publish, everyone reads s0(0) ----
    stA(0, 0); stB(0, 0); stA(0, 1); stB(0, 1);
    asm volatile("s_waitcnt vmcnt(0)" ::: "memory");
    __builtin_amdgcn_s_barrier();
    asm volatile("" ::: "memory");
    RD_A03(afA, lds, 0);
    RD_BF(bfA, lds, 0);

#pragma unroll 1
    for (int t = 0; t < NT; ++t) {
        const unsigned short* Lb  = lds + (t & 1) * BUF;
        const unsigned short* Lb2 = lds + ((t + 1) & 1) * BUF;
        const bool pf = (t + 1 < NT);

        // ---- P1: stage A(t+1) | frags A47s0 | MFMA(afA,bfA)->acc03 ----
        if (pf) { stA(t + 1, 0); stA(t + 1, 1); }
        if (grpA) {
            RD_A47(afB, Lb, 0);
            LGKM(4); SBAR;
            MM03(afA, bfA);
        } else {
            LGKM(0); SBAR;
            MM03(afA, bfA);
            SBAR;
            RD_A47(afB, Lb, 0);
        }

        // ---- P2: stage B(t+1) | frags A03s1,Bs1 | MFMA(afB,bfA)->acc47 ----
        if (pf) { stB(t + 1, 0); stB(t + 1, 1); }
        if (grpA) {
            RD_A03(afA, Lb, 1);
            RD_BF(bfB, Lb, 1);
            LGKM(8); SBAR;
            MM47(afB, bfA);
        } else {
            LGKM(0); SBAR;
            MM47(afB, bfA);
            SBAR;
            RD_A03(afA, Lb, 1);
            RD_BF(bfB, Lb, 1);
        }

        // ---- P3: frags A47s1 | MFMA(afA,bfB)->acc03 ----
        if (grpA) {
            RD_A47(afB, Lb, 1);
            LGKM(4); SBAR;
            MM03(afA, bfB);
        } else {
            LGKM(0); SBAR;
            MM03(afA, bfB);
            SBAR;
            RD_A47(afB, Lb, 1);
        }

        // ---- P4: tile-boundary sync | next-tile s0 frags | MFMA(afB,bfB) ----
        asm volatile("s_waitcnt vmcnt(0) lgkmcnt(0)" ::: "memory");
        __builtin_amdgcn_s_barrier();
        asm volatile("" ::: "memory");
        if (grpA) {
            if (pf) { RD_A03(afA, Lb2, 0); RD_BF(bfA, Lb2, 0); }
            SBAR;
            MM47(afB, bfB);
        } else {
            MM47(afB, bfB);
            SBAR;
            if (pf) { RD_A03(afA, Lb2, 0); RD_BF(bfA, Lb2, 0); }
        }
    }

    // ---- epilogue: C/D layout col = lane&15, row = (lane>>4)*4 + reg ----
    const int row0 = bm * BM + wm * 128 + q * 4;
    const int col0 = bn * BN + wn * 64 + r16;
#pragma unroll
    for (int fc = 0; fc < 4; ++fc) {
        const int n  = col0 + fc * 16;
        const float sc = scales[n];
        const float bi = bias[n];
#pragma unroll
        for (int fr = 0; fr < 8; ++fr) {
            const int m = row0 + fr * 16;
#pragma unroll
            for (int r = 0; r < 4; ++r)
                C[(size_t)(m + r) * N_OUT + n] = acc[fr][fc][r] * sc + bi;
        }
    }
}

// ---------- launch ----------

extern "C" void kernel_launch(void* const* d_in, const int* in_sizes, int n_in,
                              void* d_out, int out_size, void* d_ws, size_t ws_size,
                              hipStream_t stream) {
    const float* x      = (const float*)d_in[0];
    const int*   wq     = (const int*)d_in[1];
    const float* scales = (const float*)d_in[2];
    const float* bias   = (const float*)d_in[3];
    float*       out    = (float*)d_out;

    unsigned short* xb = (unsigned short*)d_ws;                       // 64 MiB
    unsigned short* wb = xb + (size_t)M_TOK * K_IN;                   // 32 MiB
    // ws needed: (8192*4096 + 4096*4096) * 2 = 96 MiB

    const int nx8 = (M_TOK * K_IN) / 8;   // 4194304
    const int nw8 = (N_OUT * K_IN) / 8;   // 2097152
    cvt_f32_bf16_kernel<<<nx8 / 256, 256, 0, stream>>>(x, xb, nx8);
    cvt_i32_bf16_kernel<<<nw8 / 256, 256, 0, stream>>>(wq, wb, nw8);

    const int grid = (M_TOK / BM) * (N_OUT / BN);   // 32 * 16 = 512
    gemm_bf16_kernel<<<grid, 512, 0, stream>>>(xb, wb, scales, bias, out);
}

// Round 13
// 325.808 us; speedup vs baseline: 10.8146x; 5.7180x over previous
//
#include <hip/hip_runtime.h>
#include <stdint.h>

// Problem constants (from reference setup_inputs)
#define M_TOK 8192
#define N_OUT 4096
#define K_IN  4096

// GEMM tiling: 256x256 tile, BK=64, 8 waves 2x4.
// A: LDS double-buffer (2 x 32 KiB). B: DIRECT GLOBAL->VGPR from a
// fragment-native prepass layout (no LDS, no staging DMA for B).
#define BM 256
#define BN 256
#define BK 64
#define NT (K_IN / BK)            // 64 K-tiles
#define ABUF 16384                // shorts per A buffer: 256 rows x 64 k
#define SEC 8192                  // shorts per A k-slice section (256 x 32)

typedef float floatx4 __attribute__((ext_vector_type(4)));
typedef __bf16 bf16x8 __attribute__((ext_vector_type(8)));
typedef unsigned short ushort8_t __attribute__((ext_vector_type(8)));

#define MFMA16 __builtin_amdgcn_mfma_f32_16x16x32_bf16

// ---------- helpers ----------

__device__ __forceinline__ unsigned short f32_to_bf16_rne(float f) {
    union { float f; unsigned int u; } v; v.f = f;
    unsigned int u = v.u;
    u += 0x7FFFu + ((u >> 16) & 1u);   // round-to-nearest-even; inputs have no NaN
    return (unsigned short)(u >> 16);
}

// async global->LDS, 16 bytes per lane. LDS side is wave-uniform base + lane*16.
__device__ __forceinline__ void async_copy16(const void* g, void* l) {
    __builtin_amdgcn_global_load_lds(
        (__attribute__((address_space(1))) void*)(g),
        (__attribute__((address_space(3))) void*)(l),
        16, 0, 0);
}

// ---------- pre-pass: fp32 -> bf16 (A path, unchanged) ----------

__global__ void cvt_f32_bf16_kernel(const float* __restrict__ in,
                                    unsigned short* __restrict__ out, int n8) {
    int i = blockIdx.x * 256 + threadIdx.x;
    if (i >= n8) return;
    const float4* p = (const float4*)in + (size_t)i * 2;
    float4 a = p[0];
    float4 b = p[1];
    ushort8_t o;
    o[0] = f32_to_bf16_rne(a.x); o[1] = f32_to_bf16_rne(a.y);
    o[2] = f32_to_bf16_rne(a.z); o[3] = f32_to_bf16_rne(a.w);
    o[4] = f32_to_bf16_rne(b.x); o[5] = f32_to_bf16_rne(b.y);
    o[6] = f32_to_bf16_rne(b.z); o[7] = f32_to_bf16_rne(b.w);
    *((ushort8_t*)out + i) = o;
}

// ---------- pre-pass: int32 W -> bf16 in FRAGMENT-NATIVE layout ----------
// B'[n16][kq][r16][8shorts]: short index = ((n16*512 + kq)*16 + r16)*8 + ke,
// n = n16*16 + r16, k = kq*8 + ke. A wave's MFMA B-frag (fixed n16, kq block)
// reads ONE contiguous 1 KiB window: lane l = q*16+r16 -> byte l*16 via
// global_load_dwordx4 -- perfect coalescing, zero DS involvement.
// Per-n16 stride = 512*16*8 = 65536 shorts (R12's bug: used 4096).

__global__ void cvt_wq_frag_kernel(const int* __restrict__ in,
                                   unsigned short* __restrict__ out, int n8) {
    int o = blockIdx.x * 256 + threadIdx.x;
    if (o >= n8) return;
    const int r16 = o & 15;
    const int kq  = (o >> 4) & 511;        // K/8 = 512
    const int n16 = o >> 13;               // / (512*16)
    const int n   = n16 * 16 + r16;
    const int4* p = (const int4*)(in + (size_t)n * K_IN + kq * 8);
    int4 a = p[0];
    int4 b = p[1];
    ushort8_t w;
    w[0] = f32_to_bf16_rne((float)a.x); w[1] = f32_to_bf16_rne((float)a.y);
    w[2] = f32_to_bf16_rne((float)a.z); w[3] = f32_to_bf16_rne((float)a.w);
    w[4] = f32_to_bf16_rne((float)b.x); w[5] = f32_to_bf16_rne((float)b.y);
    w[6] = f32_to_bf16_rne((float)b.z); w[7] = f32_to_bf16_rne((float)b.w);
    *((ushort8_t*)out + o) = w;
}

// ---------- GEMM: C[m][n] = sum_k A[m][k]*B[n][k]; C = acc*scale[n]+bias[n] ----------
// B-OFF-THE-DS-PIPE version of the R6 skeleton (R12 design, addressing fixed:
// n16/fc stride = 65536 shorts, q stride = 128, was 16x too small -> absmax
// 690). Measured plateau: tile time 4580 cyc = MFMA 2483 + DS ~2100
// serialized; wait-retiming neutral; role-split spills. So REDUCE THE DS
// TERM: B fragments load directly global->VGPR from the fragment-native B'
// layout (L2/L3-resident, 1 KiB fully-coalesced per frag per wave). DS
// traffic/tile: 192->128 KiB (A only); B staging DMA + LDS gone (64 KiB);
// 1 barrier/tile.
//
// Per-wave ledger per tile t (vm retires in ISSUE order; LD_B/stA = 4 each):
//  P1: issue stA(t+1) + bf(t,s1) | ds A47s0->afB |
//      vmcnt(8) [drains bf(t,s0)] | lgkm(4) [A03s0 ready] | MM03(afA,bf0)
//  P2: ds A03s1->afA | lgkm(4) [A47s0 ready] | MM47(afB,bf0)
//  P3: issue bf(t+1,s0) | ds A47s1->afB |
//      vmcnt(4) [drains bf(t,s1) AND stA(t+1); leaves bf(t+1,s0)] |
//      lgkm(4) [A03s1 ready] | MM03(afA,bf1)
//  P4: lgkm(0) [A47s1 ready] | BARRIER (publish A(t+1)) |
//      ds A03s0(t+1)->afA | MM47(afB,bf1)
// Tail t=NT-1: P1 vmcnt(4), P3 vmcnt(0). A-buffer WAR: all A(t) reads
// lgkm-drained by P4's lgkm(0) before the barrier; stA(t+2) issues after it.
// Accumulation order identical to R6 -> bit-identical numerics.
//
// A LDS: k-slice sections A_s0 | A_s1 (16 KiB each), PAIR-ROW swizzle
// (R3/R4-verified 0 conflicts): pair p = row>>1 (128 B) holds rows {2p,2p+1};
// chunk (p,c): cg = c ^ (p&7); inverse on the per-lane GLOBAL source, linear
// LDS dest. Every ds_read_b128 covers one contiguous 1 KiB window once.

__global__ __launch_bounds__(512, 2)
void gemm_bf16_kernel(const unsigned short* __restrict__ A,
                      const unsigned short* __restrict__ Bq,   // frag-native B'
                      const float* __restrict__ scales,
                      const float* __restrict__ bias,
                      float* __restrict__ C) {
    __shared__ __align__(16) unsigned short lds[2 * ABUF];   // 64 KiB

    const int tid = threadIdx.x;

    // T1: bijective XCD swizzle (nwg = 512, divisible by 8), bn-fastest.
    const int nwg = (M_TOK / BM) * (N_OUT / BN);   // 32*16 = 512
    const int cpx = nwg / 8;                        // 64
    const int wg  = (blockIdx.x % 8) * cpx + blockIdx.x / 8;
    const int bn  = wg & 15;                        // N_OUT/BN = 16
    const int bm  = wg >> 4;                        // 0..31

    const int lane = tid & 63;
    const int wave = tid >> 6;          // 0..7
    const int wm   = wave >> 2;         // 0..1 -> rows wm*128
    const int wn   = wave & 3;          // 0..3 -> cols wn*64

    // ---- A staging addressing (loop-invariant; R3-verified) ----
    const int t8 = tid >> 3;                        // 0..63
    const int cg = (tid & 7) ^ (t8 & 7);            // unswizzled chunk in pair
    const int grow0 = 2 * t8 + (cg >> 2);           // row within 128-row issue
    const int gcol0 = (cg & 3) * 8;                 // shorts within k-slice
    const unsigned short* aP = A + (size_t)(bm * BM + grow0) * K_IN + gcol0;

    auto stA = [&](int tt) {    // stage full A K-tile: 4 global_load_lds
        unsigned short* base = &lds[(tt & 1) * ABUF];
#pragma unroll
        for (int s = 0; s < 2; ++s) {
            const unsigned short* g = aP + tt * BK + s * 32;
            unsigned short* d = base + s * SEC + tid * 8;
            async_copy16(g, d);
            async_copy16(g + (size_t)128 * K_IN, d + 4096);
        }
    };

    // ---- A fragment read addressing (loop-invariant) ----
    const int r16 = lane & 15;
    const int q   = lane >> 4;                      // 0..3
    const int cr  = (((r16 & 1) << 2) + q) ^ ((r16 >> 1) & 7);
    const int aOff = (wm * 64 + (r16 >> 1)) * 64 + cr * 8;

    // ---- B fragment global addressing (loop-invariant; FIXED strides) ----
    // element (n16,kq,r16,ke) at short offset n16*65536 + kq*128 + r16*8 + ke;
    // kq = t*8 + s*4 + q. Frag (fc,t,s): bQ + fc*65536 + t*1024 + s*512.
    const unsigned short* bQ =
        Bq + (size_t)(bn * 16 + wn * 4) * 65536 + q * 128 + r16 * 8;

    floatx4 acc[8][4] = {};
    bf16x8 afA[4], afB[4], bf0[4], bf1[4];

#define RD_A03(dst, base, s)                                                   \
    { _Pragma("unroll") for (int i = 0; i < 4; ++i)                            \
        dst[i] = *(const bf16x8*)((base) + (s) * SEC + aOff + i * 512); }
#define RD_A47(dst, base, s)                                                   \
    { _Pragma("unroll") for (int i = 0; i < 4; ++i)                            \
        dst[i] = *(const bf16x8*)((base) + (s) * SEC + aOff + (4 + i) * 512); }
#define LD_B(dst, tt, s)                                                       \
    { _Pragma("unroll") for (int j = 0; j < 4; ++j)                            \
        dst[j] = *(const bf16x8*)(bQ + (size_t)(j) * 65536 + (tt) * 1024 + (s) * 512); }
#define MM03(af, bf)                                                           \
    { __builtin_amdgcn_s_setprio(1);                                           \
      _Pragma("unroll") for (int i = 0; i < 4; ++i)                            \
          _Pragma("unroll") for (int j = 0; j < 4; ++j)                        \
              acc[i][j] = MFMA16(af[i], bf[j], acc[i][j], 0, 0, 0);            \
      __builtin_amdgcn_s_setprio(0); }
#define MM47(af, bf)                                                           \
    { __builtin_amdgcn_s_setprio(1);                                           \
      _Pragma("unroll") for (int i = 0; i < 4; ++i)                            \
          _Pragma("unroll") for (int j = 0; j < 4; ++j)                        \
              acc[4 + i][j] = MFMA16(af[i], bf[j], acc[4 + i][j], 0, 0, 0);    \
      __builtin_amdgcn_s_setprio(0); }
#define SBAR __builtin_amdgcn_sched_barrier(0)

    // ---- prologue: stage A(0), load bf(0,s0), publish, read A03s0 ----
    stA(0);
    LD_B(bf0, 0, 0);
    asm volatile("s_waitcnt vmcnt(0)" ::: "memory");
    __builtin_amdgcn_s_barrier();
    asm volatile("" ::: "memory");
    RD_A03(afA, lds, 0);         // 4 reads left in flight into P1

#pragma unroll 1
    for (int t = 0; t < NT; ++t) {
        const unsigned short* Lb  = lds + (t & 1) * ABUF;
        const unsigned short* Lb2 = lds + ((t + 1) & 1) * ABUF;
        const bool pf = (t + 1 < NT);

        // ---- P1: issue sA(t+1)+bf(t,s1) | ds A47s0 | MM03(afA,bf0) ----
        if (pf) stA(t + 1);
        LD_B(bf1, t, 1);
        RD_A47(afB, Lb, 0);
        if (pf) asm volatile("s_waitcnt vmcnt(8)" ::: "memory");  // bf0 ready
        else    asm volatile("s_waitcnt vmcnt(4)" ::: "memory");
        asm volatile("s_waitcnt lgkmcnt(4)" ::: "memory");        // afA ready
        SBAR;
        MM03(afA, bf0);

        // ---- P2: ds A03s1 | MM47(afB,bf0) ----
        RD_A03(afA, Lb, 1);
        asm volatile("s_waitcnt lgkmcnt(4)" ::: "memory");        // afB ready
        SBAR;
        MM47(afB, bf0);

        // ---- P3: issue bf(t+1,s0) | ds A47s1 | MM03(afA,bf1) ----
        if (pf) LD_B(bf0, t + 1, 0);
        RD_A47(afB, Lb, 1);
        if (pf) asm volatile("s_waitcnt vmcnt(4)" ::: "memory");  // bf1 ready, sA done
        else    asm volatile("s_waitcnt vmcnt(0)" ::: "memory");
        asm volatile("s_waitcnt lgkmcnt(4)" ::: "memory");        // afA(s1) ready
        SBAR;
        MM03(afA, bf1);

        // ---- P4: publish A(t+1) | ds A03s0(t+1) | MM47(afB,bf1) ----
        asm volatile("s_waitcnt lgkmcnt(0)" ::: "memory");        // afB(s1) ready
        __builtin_amdgcn_s_barrier();
        asm volatile("" ::: "memory");
        if (pf) RD_A03(afA, Lb2, 0);
        SBAR;
        MM47(afB, bf1);
    }

    // ---- epilogue: C/D layout col = lane&15, row = (lane>>4)*4 + reg ----
    const int row0 = bm * BM + wm * 128 + q * 4;
    const int col0 = bn * BN + wn * 64 + r16;
#pragma unroll
    for (int fc = 0; fc < 4; ++fc) {
        const int n  = col0 + fc * 16;
        const float sc = scales[n];
        const float bi = bias[n];
#pragma unroll
        for (int fr = 0; fr < 8; ++fr) {
            const int m = row0 + fr * 16;
#pragma unroll
            for (int r = 0; r < 4; ++r)
                C[(size_t)(m + r) * N_OUT + n] = acc[fr][fc][r] * sc + bi;
        }
    }
}

// ---------- launch ----------

extern "C" void kernel_launch(void* const* d_in, const int* in_sizes, int n_in,
                              void* d_out, int out_size, void* d_ws, size_t ws_size,
                              hipStream_t stream) {
    const float* x      = (const float*)d_in[0];
    const int*   wq     = (const int*)d_in[1];
    const float* scales = (const float*)d_in[2];
    const float* bias   = (const float*)d_in[3];
    float*       out    = (float*)d_out;

    unsigned short* xb = (unsigned short*)d_ws;                       // 64 MiB
    unsigned short* wb = xb + (size_t)M_TOK * K_IN;                   // 32 MiB
    // ws needed: (8192*4096 + 4096*4096) * 2 = 96 MiB

    const int nx8 = (M_TOK * K_IN) / 8;   // 4194304
    const int nw8 = (N_OUT * K_IN) / 8;   // 2097152
    cvt_f32_bf16_kernel<<<nx8 / 256, 256, 0, stream>>>(x, xb, nx8);
    cvt_wq_frag_kernel<<<nw8 / 256, 256, 0, stream>>>(wq, wb, nw8);

    const int grid = (M_TOK / BM) * (N_OUT / BN);   // 32 * 16 = 512
    gemm_bf16_kernel<<<grid, 512, 0, stream>>>(xb, wb, scales, bias, out);
}

// Round 14
// 187.758 us; speedup vs baseline: 18.7661x; 1.7353x over previous
//
#include <hip/hip_runtime.h>
#include <stdint.h>

// Problem constants (from reference setup_inputs)
#define M_TOK 8192
#define N_OUT 4096
#define K_IN  4096

// INT8 GEMM: 256x256 tile, BK=128, double-buffered LDS (128 KiB), 8 waves 2x4.
// W is EXACTLY int8 (reference stores int8 values in int32); x quantized
// per-token to int8 (sx = rowmax/127). Inner product exact in int32.
#define BM 256
#define BN 256
#define BK 128
#define NT (K_IN / BK)            // 32 K-tiles
#define SEC 16384                 // bytes per k-slice section (256 rows x 64 B)
#define BUF 65536                 // bytes per buffer (A_s0|A_s1|B_s0|B_s1)

typedef int intx4 __attribute__((ext_vector_type(4)));

#define MFMAI8 __builtin_amdgcn_mfma_i32_16x16x64_i8

// ---------- helpers ----------

// async global->LDS, 16 bytes per lane. LDS side is wave-uniform base + lane*16.
__device__ __forceinline__ void async_copy16(const void* g, void* l) {
    __builtin_amdgcn_global_load_lds(
        (__attribute__((address_space(1))) void*)(g),
        (__attribute__((address_space(3))) void*)(l),
        16, 0, 0);
}

// ---------- pre-pass 1: x fp32 -> int8 per-token (sx = rowmax/127, RNE) ----------
// One block per token row (4096 f32). Thread i owns elements [i*16, i*16+16).

__global__ void quant_x_kernel(const float* __restrict__ in,
                               int8_t* __restrict__ out,
                               float* __restrict__ sx) {
    const int row = blockIdx.x;
    const int tid = threadIdx.x;
    const float4* p = (const float4*)(in + (size_t)row * K_IN + tid * 16);
    float4 v0 = p[0], v1 = p[1], v2 = p[2], v3 = p[3];

    float m = fabsf(v0.x);
    m = fmaxf(m, fabsf(v0.y)); m = fmaxf(m, fabsf(v0.z)); m = fmaxf(m, fabsf(v0.w));
    m = fmaxf(m, fabsf(v1.x)); m = fmaxf(m, fabsf(v1.y));
    m = fmaxf(m, fabsf(v1.z)); m = fmaxf(m, fabsf(v1.w));
    m = fmaxf(m, fabsf(v2.x)); m = fmaxf(m, fabsf(v2.y));
    m = fmaxf(m, fabsf(v2.z)); m = fmaxf(m, fabsf(v2.w));
    m = fmaxf(m, fabsf(v3.x)); m = fmaxf(m, fabsf(v3.y));
    m = fmaxf(m, fabsf(v3.z)); m = fmaxf(m, fabsf(v3.w));

    // wave (64) then block (4 waves) max-reduce
#pragma unroll
    for (int off = 32; off; off >>= 1) m = fmaxf(m, __shfl_xor(m, off));
    __shared__ float wmax[4];
    if ((tid & 63) == 0) wmax[tid >> 6] = m;
    __syncthreads();
    m = fmaxf(fmaxf(wmax[0], wmax[1]), fmaxf(wmax[2], wmax[3]));
    m = fmaxf(m, 1e-20f);

    const float rs = 127.0f / m;
    if (tid == 0) sx[row] = m * (1.0f / 127.0f);

    union { int4 v; int8_t c[16]; } u;
    u.c[0]  = (int8_t)__float2int_rn(v0.x * rs);
    u.c[1]  = (int8_t)__float2int_rn(v0.y * rs);
    u.c[2]  = (int8_t)__float2int_rn(v0.z * rs);
    u.c[3]  = (int8_t)__float2int_rn(v0.w * rs);
    u.c[4]  = (int8_t)__float2int_rn(v1.x * rs);
    u.c[5]  = (int8_t)__float2int_rn(v1.y * rs);
    u.c[6]  = (int8_t)__float2int_rn(v1.z * rs);
    u.c[7]  = (int8_t)__float2int_rn(v1.w * rs);
    u.c[8]  = (int8_t)__float2int_rn(v2.x * rs);
    u.c[9]  = (int8_t)__float2int_rn(v2.y * rs);
    u.c[10] = (int8_t)__float2int_rn(v2.z * rs);
    u.c[11] = (int8_t)__float2int_rn(v2.w * rs);
    u.c[12] = (int8_t)__float2int_rn(v3.x * rs);
    u.c[13] = (int8_t)__float2int_rn(v3.y * rs);
    u.c[14] = (int8_t)__float2int_rn(v3.z * rs);
    u.c[15] = (int8_t)__float2int_rn(v3.w * rs);
    ((int4*)(out + (size_t)row * K_IN))[tid] = u.v;
}

// ---------- pre-pass 2: W int32 (int8-valued) -> int8 pack (EXACT) ----------

__global__ void quant_w_kernel(const int* __restrict__ in,
                               int8_t* __restrict__ out, int n16) {
    int i = blockIdx.x * 256 + threadIdx.x;   // handles 16 elements
    if (i >= n16) return;
    const int4* p = (const int4*)in + (size_t)i * 4;
    int4 a = p[0], b = p[1], c = p[2], d = p[3];
    union { int4 v; int8_t q[16]; } u;
    u.q[0]  = (int8_t)a.x; u.q[1]  = (int8_t)a.y; u.q[2]  = (int8_t)a.z; u.q[3]  = (int8_t)a.w;
    u.q[4]  = (int8_t)b.x; u.q[5]  = (int8_t)b.y; u.q[6]  = (int8_t)b.z; u.q[7]  = (int8_t)b.w;
    u.q[8]  = (int8_t)c.x; u.q[9]  = (int8_t)c.y; u.q[10] = (int8_t)c.z; u.q[11] = (int8_t)c.w;
    u.q[12] = (int8_t)d.x; u.q[13] = (int8_t)d.y; u.q[14] = (int8_t)d.z; u.q[15] = (int8_t)d.w;
    ((int4*)out)[i] = u.v;
}

// ---------- GEMM: C[m][n] = sx[m]*scales[n]*(sum_k xq*wq) + bias[n] ----------
// R6's verified 4-phase single-sync skeleton transplanted to i8 / BK=128.
// mfma_i32_16x16x64_i8: A row = lane&15, k = (lane>>4)*16 + j (16 consecutive
// bytes/lane -- gfx950 2xK extension of the verified bf16 mapping); C/D layout
// dtype-independent (col = lane&15, row = (lane>>4)*4 + reg). Per wave per
// K=128 tile: 24 ds_read_b128 + 64 MFMA -- same cycles as the bf16 K=64 tile
// but double the K coverage. NT = 32.
//
// Ledger (identical to R6; DS in-order per wave; stage = 8 gloads in P1/P2):
//  P1: stage A(t+1) s0,s1 | read A47s0->afB (4) | lgkm(4) [drains prev 8] |
//      MM03(afA,bfA)   [slice s0]
//  P2: stage B(t+1) s0,s1 | read A03s1->afA, Bs1->bfB (8) | lgkm(8) |
//      MM47(afB,bfA)   [s0]
//  P3: read A47s1->afB (4) | lgkm(4) | MM03(afA,bfB)   [s1]
//  P4: vmcnt(0)+lgkm(0) [stages issued 2-3 phases earlier] | BARRIER |
//      read A03s0',Bs0' (8, next buf) | MM47(afB,bfB)  [s1]
// Hazards identical to R6 (verified): all buf(t) reads lgkm-drained before
// the boundary barrier; stage(t+2) issues after it; buf(t+1) reads follow
// every wave's vmcnt(0)+barrier.
//
// LDS: byte sections A_s0|A_s1|B_s0|B_s1 (16 KiB each = 256 rows x 64 B),
// PAIR-ROW swizzle (R3/R4-verified 0 conflicts; formulas unchanged, shorts->
// bytes): pair p = row>>1 (128 B) holds rows {2p,2p+1}; chunk (p,c) 16 B:
// cg = c ^ (p&7); inverse on the per-lane GLOBAL source, linear LDS dest.
// Every ds_read_b128 covers one contiguous 1 KiB window exactly once.

__global__ __launch_bounds__(512, 2)
void gemm_i8_kernel(const int8_t* __restrict__ A,
                    const int8_t* __restrict__ B,
                    const float* __restrict__ sx,
                    const float* __restrict__ scales,
                    const float* __restrict__ bias,
                    float* __restrict__ C) {
    __shared__ __align__(16) int8_t lds[2 * BUF];   // 128 KiB

    const int tid = threadIdx.x;

    // T1: bijective XCD swizzle (nwg = 512, divisible by 8), bn-fastest.
    const int nwg = (M_TOK / BM) * (N_OUT / BN);   // 32*16 = 512
    const int cpx = nwg / 8;                        // 64
    const int wg  = (blockIdx.x % 8) * cpx + blockIdx.x / 8;
    const int bn  = wg & 15;                        // N_OUT/BN = 16
    const int bm  = wg >> 4;                        // 0..31

    const int lane = tid & 63;
    const int wave = tid >> 6;          // 0..7
    const int wm   = wave >> 2;         // 0..1 -> rows wm*128
    const int wn   = wave & 3;          // 0..3 -> cols wn*64

    // ---- staging addressing (pair-row inverse swizzle, bytes) ----
    // One issue = 512 lanes x 16 B = 8 KiB = 64 pairs = 128 rows of a 64B slice.
    const int t8 = tid >> 3;                        // 0..63
    const int cg = (tid & 7) ^ (t8 & 7);            // unswizzled chunk in pair
    const int grow0 = 2 * t8 + (cg >> 2);           // row within 128-row issue
    const int gcol0 = (cg & 3) * 16;                // bytes within 64B slice
    const int8_t* aP = A + (size_t)(bm * BM + grow0) * K_IN + gcol0;
    const int8_t* bP = B + (size_t)(bn * BN + grow0) * K_IN + gcol0;

    auto stA = [&](int tt, int s) {
        int8_t* d = &lds[(tt & 1) * BUF + s * SEC + tid * 16];
        const int8_t* g = aP + (size_t)tt * BK + s * 64;
        async_copy16(g, d);
        async_copy16(g + (size_t)128 * K_IN, d + 8192);
    };
    auto stB = [&](int tt, int s) {
        int8_t* d = &lds[(tt & 1) * BUF + 2 * SEC + s * SEC + tid * 16];
        const int8_t* g = bP + (size_t)tt * BK + s * 64;
        async_copy16(g, d);
        async_copy16(g + (size_t)128 * K_IN, d + 8192);
    };

    // ---- fragment read addressing ----
    // Frag row R: pair p = R>>1, chunk c = ((R&1)*4 + q) ^ ((R>>1)&7), 16 B.
    const int r16 = lane & 15;
    const int q   = lane >> 4;                      // k-chunk (16 B) in slice
    const int cr  = (((r16 & 1) << 2) + q) ^ ((r16 >> 1) & 7);
    const int aOff = (wm * 64 + (r16 >> 1)) * 128 + cr * 16;
    const int bOff = 2 * SEC + (wn * 32 + (r16 >> 1)) * 128 + cr * 16;

    intx4 acc[8][4] = {};
    intx4 afA[4], afB[4], bfA[4], bfB[4];

#define RD_A03(dst, base, s)                                                   \
    { _Pragma("unroll") for (int i = 0; i < 4; ++i)                            \
        dst[i] = *(const intx4*)((base) + (s) * SEC + aOff + i * 1024); }
#define RD_A47(dst, base, s)                                                   \
    { _Pragma("unroll") for (int i = 0; i < 4; ++i)                            \
        dst[i] = *(const intx4*)((base) + (s) * SEC + aOff + (4 + i) * 1024); }
#define RD_BF(dst, base, s)                                                    \
    { _Pragma("unroll") for (int j = 0; j < 4; ++j)                            \
        dst[j] = *(const intx4*)((base) + (s) * SEC + bOff + j * 1024); }
#define MM03(af, bf)                                                           \
    { __builtin_amdgcn_s_setprio(1);                                           \
      _Pragma("unroll") for (int i = 0; i < 4; ++i)                            \
          _Pragma("unroll") for (int j = 0; j < 4; ++j)                        \
              acc[i][j] = MFMAI8(af[i], bf[j], acc[i][j], 0, 0, 0);            \
      __builtin_amdgcn_s_setprio(0); }
#define MM47(af, bf)                                                           \
    { __builtin_amdgcn_s_setprio(1);                                           \
      _Pragma("unroll") for (int i = 0; i < 4; ++i)                            \
          _Pragma("unroll") for (int j = 0; j < 4; ++j)                        \
              acc[4 + i][j] = MFMAI8(af[i], bf[j], acc[4 + i][j], 0, 0, 0);    \
      __builtin_amdgcn_s_setprio(0); }
#define SBAR __builtin_amdgcn_sched_barrier(0)

    // ---- prologue: stage tile 0, publish, read s0 frags (8 left in flight) ----
    stA(0, 0); stB(0, 0); stA(0, 1); stB(0, 1);
    asm volatile("s_waitcnt vmcnt(0)" ::: "memory");
    __builtin_amdgcn_s_barrier();
    asm volatile("" ::: "memory");
    RD_A03(afA, lds, 0);
    RD_BF(bfA, lds, 0);

#pragma unroll 1
    for (int t = 0; t < NT; ++t) {
        const int8_t* Lb  = lds + (t & 1) * BUF;
        const int8_t* Lb2 = lds + ((t + 1) & 1) * BUF;
        const bool pf = (t + 1 < NT);

        // ---- P1: stage A(t+1) | read A47s0 | MM03(afA,bfA) ----
        if (pf) { stA(t + 1, 0); stA(t + 1, 1); }
        RD_A47(afB, Lb, 0);
        asm volatile("s_waitcnt lgkmcnt(4)" ::: "memory");
        SBAR;
        MM03(afA, bfA);

        // ---- P2: stage B(t+1) | read A03s1, Bs1 | MM47(afB,bfA) ----
        if (pf) { stB(t + 1, 0); stB(t + 1, 1); }
        RD_A03(afA, Lb, 1);
        RD_BF(bfB, Lb, 1);
        asm volatile("s_waitcnt lgkmcnt(8)" ::: "memory");
        SBAR;
        MM47(afB, bfA);

        // ---- P3: read A47s1 | MM03(afA,bfB) ----
        RD_A47(afB, Lb, 1);
        asm volatile("s_waitcnt lgkmcnt(4)" ::: "memory");
        SBAR;
        MM03(afA, bfB);

        // ---- P4: boundary sync | read next s0 frags | MM47(afB,bfB) ----
        asm volatile("s_waitcnt vmcnt(0) lgkmcnt(0)" ::: "memory");
        __builtin_amdgcn_s_barrier();
        asm volatile("" ::: "memory");
        if (pf) {
            RD_A03(afA, Lb2, 0);
            RD_BF(bfA, Lb2, 0);
        }
        SBAR;
        MM47(afB, bfB);
    }

    // ---- epilogue: C/D col = lane&15, row = (lane>>4)*4 + reg (dtype-indep) ----
    const int row0 = bm * BM + wm * 128 + q * 4;
    const int col0 = bn * BN + wn * 64 + r16;
    float sxv[8][4];
#pragma unroll
    for (int fr = 0; fr < 8; ++fr)
#pragma unroll
        for (int r = 0; r < 4; ++r)
            sxv[fr][r] = sx[row0 + fr * 16 + r];
#pragma unroll
    for (int fc = 0; fc < 4; ++fc) {
        const int n  = col0 + fc * 16;
        const float sc = scales[n];
        const float bi = bias[n];
#pragma unroll
        for (int fr = 0; fr < 8; ++fr) {
            const int m = row0 + fr * 16;
#pragma unroll
            for (int r = 0; r < 4; ++r)
                C[(size_t)(m + r) * N_OUT + n] =
                    (float)acc[fr][fc][r] * (sxv[fr][r] * sc) + bi;
        }
    }
}

// ---------- launch ----------

extern "C" void kernel_launch(void* const* d_in, const int* in_sizes, int n_in,
                              void* d_out, int out_size, void* d_ws, size_t ws_size,
                              hipStream_t stream) {
    const float* x      = (const float*)d_in[0];
    const int*   wq     = (const int*)d_in[1];
    const float* scales = (const float*)d_in[2];
    const float* bias   = (const float*)d_in[3];
    float*       out    = (float*)d_out;

    int8_t* xq = (int8_t*)d_ws;                               // 32 MiB
    int8_t* wb = xq + (size_t)M_TOK * K_IN;                   // 16 MiB
    float*  sx = (float*)(wb + (size_t)N_OUT * K_IN);         // 32 KiB
    // ws needed: 48 MiB + 32 KiB (<< previous 96 MiB usage)

    quant_x_kernel<<<M_TOK, 256, 0, stream>>>(x, xq, sx);
    const int nw16 = (N_OUT * K_IN) / 16;   // 1048576
    quant_w_kernel<<<nw16 / 256, 256, 0, stream>>>(wq, wb, nw16);

    const int grid = (M_TOK / BM) * (N_OUT / BN);   // 32 * 16 = 512
    gemm_i8_kernel<<<grid, 512, 0, stream>>>(xq, wb, sx, scales, bias, out);
}